// Round 11
// baseline (156.924 us; speedup 1.0000x reference)
//
#include <hip/hip_runtime.h>
#include <math.h>

// Problem constants
#define NROWS 16384                     // B*S
#define HIDDEN 1024
#define NVARS 320
#define NCOLS 640
#define CVDIM 256
#define OUT_ELEMS (NROWS * CVDIM)

typedef __attribute__((ext_vector_type(8))) short short8;
typedef __attribute__((ext_vector_type(4))) float floatx4;

__device__ __forceinline__ unsigned f32_to_bf16(float f) {
    unsigned u = __builtin_bit_cast(unsigned, f);
    return (u + 0x7FFFu + ((u >> 16) & 1u)) >> 16;
}
__device__ __forceinline__ float bf16_to_f32(ushort u) {
    return __builtin_bit_cast(float, ((unsigned)u) << 16);
}
// HW packed f32->bf16 RTNE: dst.lo16 = bf16(a), dst.hi16 = bf16(b)
__device__ __forceinline__ unsigned cvtpk(float a, float b) {
    unsigned r;
    asm("v_cvt_pk_bf16_f32 %0, %1, %2" : "=v"(r) : "v"(a), "v"(b));
    return r;
}

__global__ __launch_bounds__(256) void convert_bf16_kernel(
    const float* __restrict__ src, ushort* __restrict__ dst, int n8)
{
    const int i = blockIdx.x * 256 + threadIdx.x;
    if (i >= n8) return;
    const float4* s = reinterpret_cast<const float4*>(src) + (size_t)i * 2;
    const float4 v0 = s[0];
    const float4 v1 = s[1];
    uint4 p;
    p.x = f32_to_bf16(v0.x) | (f32_to_bf16(v0.y) << 16);
    p.y = f32_to_bf16(v0.z) | (f32_to_bf16(v0.w) << 16);
    p.z = f32_to_bf16(v1.x) | (f32_to_bf16(v1.y) << 16);
    p.w = f32_to_bf16(v1.z) | (f32_to_bf16(v1.w) << 16);
    reinterpret_cast<uint4*>(dst)[i] = p;
}

__device__ __forceinline__ void async16(const void* g, void* l) {
    __builtin_amdgcn_global_load_lds(
        (const __attribute__((address_space(1))) void*)g,
        (__attribute__((address_space(3))) void*)l,
        16, 0, 0);
}

// ---------------- GEMM: logits(bf16) = X(f32) @ Wbf^T + bias ----------------
// 128x128x32 tile, 4 waves (2x2), wave tile 64x64.
// A: NO LDS — each lane loads its own 8 f32 per fragment directly from X
//    (reg double-buffered one K-step ahead), converts via v_cvt_pk_bf16_f32.
// B: bf16 via global_load_lds, 2x8KB double buffer, 1 barrier per K-step.
#define GBM 128
#define GBN 128
#define GBK 32

__global__ __launch_bounds__(256, 2) void gemm_logits_kernel(
    const float* __restrict__ X,        // [16384,1024] f32
    const ushort* __restrict__ Wbf,     // [640,1024] bf16
    const float* __restrict__ bias,     // [640]
    ushort* __restrict__ Lg)            // [16384,640] bf16
{
    __shared__ __align__(16) ushort ldsB[8192];   // two [128][32] bf16 buffers

    const int tid = threadIdx.x;
    const int lane = tid & 63;
    const int w = tid >> 6;
    const int wm = w >> 1, wn = w & 1;

    // XCD chunked swizzle: 640 blocks = 8 XCDs x 80; within XCD walk n fastest
    const int bid = blockIdx.x;
    const int wg = (bid & 7) * 80 + (bid >> 3);
    const int m0 = (wg / 5) * GBM;
    const int n0 = (wg % 5) * GBN;

    const int rm = lane & 15;
    const int kc = lane >> 4;   // 0..3

    floatx4 acc[4][4];
#pragma unroll
    for (int i = 0; i < 4; ++i)
#pragma unroll
        for (int j = 0; j < 4; ++j) acc[i][j] = (floatx4){0.f, 0.f, 0.f, 0.f};

    // per-lane A fragment row pointers
    const float* Ab[4];
#pragma unroll
    for (int f = 0; f < 4; ++f)
        Ab[f] = X + (size_t)(m0 + wm * 64 + f * 16 + rm) * HIDDEN + kc * 8;

#define ISSUE_B(boff, kk) {                                                    \
    int c = tid;                                                               \
    async16(Wbf + (size_t)(n0 + (c >> 2)) * HIDDEN + (kk) + (c & 3) * 8,       \
            ldsB + (boff) + c * 8);                                            \
    c = tid + 256;                                                             \
    async16(Wbf + (size_t)(n0 + (c >> 2)) * HIDDEN + (kk) + (c & 3) * 8,       \
            ldsB + (boff) + c * 8); }

    float4 aLo[4], aHi[4], nLo[4], nHi[4];
#pragma unroll
    for (int f = 0; f < 4; ++f) {
        aLo[f] = *(const float4*)(Ab[f]);
        aHi[f] = *(const float4*)(Ab[f] + 4);
    }
    ISSUE_B(0, 0);
    __syncthreads();

#define STEP(CLO, CHI, NLO, NHI, T, BCUR, BNXT)                                \
    {                                                                          \
        if ((T) < 31) {                                                        \
            ISSUE_B(BNXT, ((T) + 1) * GBK);                                    \
            _Pragma("unroll")                                                  \
            for (int f = 0; f < 4; ++f) {                                      \
                NLO[f] = *(const float4*)(Ab[f] + ((T) + 1) * GBK);            \
                NHI[f] = *(const float4*)(Ab[f] + ((T) + 1) * GBK + 4);        \
            }                                                                  \
        }                                                                      \
        short8 af[4], bfr[4];                                                  \
        _Pragma("unroll")                                                      \
        for (int f = 0; f < 4; ++f) {                                          \
            union { short8 s; unsigned u[4]; } pk;                             \
            pk.u[0] = cvtpk(CLO[f].x, CLO[f].y);                               \
            pk.u[1] = cvtpk(CLO[f].z, CLO[f].w);                               \
            pk.u[2] = cvtpk(CHI[f].x, CHI[f].y);                               \
            pk.u[3] = cvtpk(CHI[f].z, CHI[f].w);                               \
            af[f] = pk.s;                                                      \
            bfr[f] = *(const short8*)(ldsB + (BCUR) +                          \
                                      ((wn * 64 + f * 16 + rm) * 4 + kc) * 8); \
        }                                                                      \
        _Pragma("unroll")                                                      \
        for (int i = 0; i < 4; ++i)                                            \
            _Pragma("unroll")                                                  \
            for (int j = 0; j < 4; ++j)                                        \
                acc[i][j] = __builtin_amdgcn_mfma_f32_16x16x32_bf16(           \
                    af[i], bfr[j], acc[i][j], 0, 0, 0);                        \
        __syncthreads();                                                       \
    }

    for (int t2 = 0; t2 < 16; ++t2) {
        STEP(aLo, aHi, nLo, nHi, 2 * t2, 0, 4096);
        STEP(nLo, nHi, aLo, aHi, 2 * t2 + 1, 4096, 0);
    }

    // epilogue: bias, cvt bf16, pair-pack via shfl, uint stores (even lanes)
    const int cl = lane & 15;
    const int r4 = (lane >> 4) * 4;
    float bj[4];
#pragma unroll
    for (int j = 0; j < 4; ++j) bj[j] = bias[n0 + wn * 64 + j * 16 + cl];

#pragma unroll
    for (int i = 0; i < 4; ++i)
#pragma unroll
        for (int j = 0; j < 4; ++j) {
            const int col = n0 + wn * 64 + j * 16 + cl;
#pragma unroll
            for (int q = 0; q < 4; ++q) {
                const int row = m0 + wm * 64 + i * 16 + r4 + q;
                unsigned v = f32_to_bf16(acc[i][j][q] + bj[j]);
                unsigned o = (unsigned)__shfl_xor((int)v, 1);
                if ((cl & 1) == 0)
                    *reinterpret_cast<uint*>(Lg + (size_t)row * NCOLS + col) =
                        v | (o << 16);
            }
        }
}

// ---------------- Quantize: gumbel-argmax / gather / softmax-marginal ----------------
// 32768 logit-rows; block = 32 rows (4 waves x 8 tasks). All gu/Lg loads
// batch-prefetched into registers before the compute chains.
__global__ __launch_bounds__(256) void quantize_kernel(
    const ushort* __restrict__ Lg,      // [16384,640] bf16
    const float* __restrict__ gu,       // [32768,320]
    const float* __restrict__ cv,       // [640,128]
    float* __restrict__ out,            // [16384,256]
    float* __restrict__ marginal)       // [640]
{
    __shared__ float smr[4][NVARS];
    const int tid = threadIdx.x;
    const int w = tid >> 6;
    const int lane = tid & 63;
    const int g = w & 1;               // each wave's rows share one group

    // batch prefetch: 8 tasks x (5 gu + 5 logits) per lane
    float ug[8][5], lg[8][5];
#pragma unroll
    for (int t = 0; t < 8; ++t) {
        const int r = blockIdx.x * 32 + t * 4 + w;
        const int n = r >> 1;
        const float* gp = gu + (size_t)r * NVARS + lane;
        const ushort* lp = Lg + (size_t)n * NCOLS + g * NVARS + lane;
#pragma unroll
        for (int j = 0; j < 5; ++j) {
            ug[t][j] = gp[j * 64];
            lg[t][j] = bf16_to_f32(lp[j * 64]);
        }
    }

    float macc[5];
#pragma unroll
    for (int j = 0; j < 5; ++j) macc[j] = 0.f;

#pragma unroll
    for (int t = 0; t < 8; ++t) {
        const int r = blockIdx.x * 32 + t * 4 + w;
        const int n = r >> 1;

        // argmax over key = lg - log(-log(u)), first-index tie-break
        float bk = lg[t][0] - __logf(-__logf(ug[t][0]));
        int bi = lane;
#pragma unroll
        for (int j = 1; j < 5; ++j) {
            const float kj = lg[t][j] - __logf(-__logf(ug[t][j]));
            const int v = lane + j * 64;
            if (kj > bk) { bk = kj; bi = v; }
        }
#pragma unroll
        for (int sh = 32; sh > 0; sh >>= 1) {
            const float ok = __shfl_xor(bk, sh);
            const int oi = __shfl_xor(bi, sh);
            if (ok > bk || (ok == bk && oi < bi)) { bk = ok; bi = oi; }
        }

        // softmax without max-subtraction (logits bounded ~|3.5|)
        float p[5], sume = 0.f;
#pragma unroll
        for (int j = 0; j < 5; ++j) { p[j] = __expf(lg[t][j]); sume += p[j]; }
#pragma unroll
        for (int sh = 32; sh > 0; sh >>= 1) sume += __shfl_xor(sume, sh);
        const float inv = 1.f / sume;
#pragma unroll
        for (int j = 0; j < 5; ++j) macc[j] += p[j] * inv;

        // gather selected codevector (128 f32 -> float2/lane)
        const float2* cvrow =
            reinterpret_cast<const float2*>(cv + (size_t)(g * NVARS + bi) * 128);
        reinterpret_cast<float2*>(out + (size_t)n * CVDIM + g * 128)[lane] = cvrow[lane];
    }

    // block-level marginal reduce: waves 0,2 -> group0; 1,3 -> group1
#pragma unroll
    for (int j = 0; j < 5; ++j) smr[w][lane + j * 64] = macc[j];
    __syncthreads();
    for (int i = tid; i < NVARS; i += 256) {
        atomicAdd(&marginal[i], smr[0][i] + smr[2][i]);
        atomicAdd(&marginal[NVARS + i], smr[1][i] + smr[3][i]);
    }
}

// ---------------- Perplexity finalize ----------------
__global__ void perplexity_kernel(const float* __restrict__ marginal,
                                  float* __restrict__ out)
{
    const int lane = threadIdx.x;
    float h0 = 0.0f, h1 = 0.0f;
    for (int v = lane; v < NVARS; v += 64) {
        const float m0 = marginal[v] * (1.0f / (float)NROWS);
        h0 += m0 * logf(m0 + 1e-7f);
        const float m1 = marginal[NVARS + v] * (1.0f / (float)NROWS);
        h1 += m1 * logf(m1 + 1e-7f);
    }
#pragma unroll
    for (int s = 32; s > 0; s >>= 1) {
        h0 += __shfl_xor(h0, s);
        h1 += __shfl_xor(h1, s);
    }
    if (lane == 0) out[OUT_ELEMS] = expf(-h0) + expf(-h1);
}

extern "C" void kernel_launch(void* const* d_in, const int* in_sizes, int n_in,
                              void* d_out, int out_size, void* d_ws, size_t ws_size,
                              hipStream_t stream) {
    const float* X    = (const float*)d_in[0];   // [8,2048,1024]
    const float* W    = (const float*)d_in[1];   // [640,1024]
    const float* bias = (const float*)d_in[2];   // [640]
    const float* cv   = (const float*)d_in[3];   // [1,640,128]
    const float* gu   = (const float*)d_in[4];   // [32768,320]
    float* out = (float*)d_out;

    ushort* Wbf      = (ushort*)d_ws;                             // 1.31 MB
    ushort* Lg       = Wbf + (size_t)NCOLS * HIDDEN;              // 20.97 MB
    float*  marginal = (float*)(Lg + (size_t)NROWS * NCOLS);      // 2.56 KB

    (void)hipMemsetAsync(marginal, 0, NCOLS * sizeof(float), stream);

    convert_bf16_kernel<<<(NCOLS * HIDDEN / 8 + 255) / 256, 256, 0, stream>>>(
        W, Wbf, NCOLS * HIDDEN / 8);

    gemm_logits_kernel<<<(NROWS / GBM) * (NCOLS / GBN), 256, 0, stream>>>(
        X, Wbf, bias, Lg);

    quantize_kernel<<<(NROWS * 2) / 32, 256, 0, stream>>>(
        Lg, gu, cv, out, marginal);

    perplexity_kernel<<<1, 64, 0, stream>>>(marginal, out);
}

// Round 12
// 101.394 us; speedup vs baseline: 1.5477x; 1.5477x over previous
//
#include <hip/hip_runtime.h>
#include <math.h>

// Problem constants
#define NROWS 16384                     // B*S
#define HIDDEN 1024
#define NVARS 320
#define NCOLS 640
#define CVDIM 256
#define OUT_ELEMS (NROWS * CVDIM)

typedef __attribute__((ext_vector_type(8))) short short8;
typedef __attribute__((ext_vector_type(4))) float floatx4;

__device__ __forceinline__ unsigned f32_to_bf16(float f) {
    unsigned u = __builtin_bit_cast(unsigned, f);
    return (u + 0x7FFFu + ((u >> 16) & 1u)) >> 16;
}
__device__ __forceinline__ float bf16_to_f32(ushort u) {
    return __builtin_bit_cast(float, ((unsigned)u) << 16);
}

__global__ __launch_bounds__(256) void convert_bf16_kernel(
    const float* __restrict__ src, ushort* __restrict__ dst, int n8)
{
    const int i = blockIdx.x * 256 + threadIdx.x;
    if (i >= n8) return;
    const float4* s = reinterpret_cast<const float4*>(src) + (size_t)i * 2;
    const float4 v0 = s[0];
    const float4 v1 = s[1];
    uint4 p;
    p.x = f32_to_bf16(v0.x) | (f32_to_bf16(v0.y) << 16);
    p.y = f32_to_bf16(v0.z) | (f32_to_bf16(v0.w) << 16);
    p.z = f32_to_bf16(v1.x) | (f32_to_bf16(v1.y) << 16);
    p.w = f32_to_bf16(v1.z) | (f32_to_bf16(v1.w) << 16);
    reinterpret_cast<uint4*>(dst)[i] = p;
}

__device__ __forceinline__ void async16(const void* g, void* l) {
    __builtin_amdgcn_global_load_lds(
        (const __attribute__((address_space(1))) void*)g,
        (__attribute__((address_space(3))) void*)l,
        16, 0, 0);
}

// ---------------- GEMM (R2 structure): Lg(bf16) = Xbf @ Wbf^T + bias ----------
// 128x128x32 tile, 256 threads = 4 waves (2x2), wave tile 64x64.
// BOTH operands bf16 via global_load_lds, single-buffered, 2 barriers/step.
// XCD-grouped mapping: the 5 n-tiles of each m-tile run adjacent on one XCD
// so the X panel is HBM-read once, L2-hit 4x.
#define GBM 128
#define GBN 128
#define GBK 32

__global__ __launch_bounds__(256) void gemm_logits_kernel(
    const ushort* __restrict__ Xbf,     // [16384,1024] bf16
    const ushort* __restrict__ Wbf,     // [640,1024] bf16
    const float* __restrict__ bias,     // [640]
    ushort* __restrict__ Lg)            // [16384,640] bf16
{
    __shared__ __align__(16) ushort As[4096];   // [128][32] bf16
    __shared__ __align__(16) ushort Bs[4096];

    const int tid = threadIdx.x;
    const int lane = tid & 63;
    const int w = tid >> 6;
    const int wm = w >> 1, wn = w & 1;

    // XCD-grouped swizzle: xcd = bid&7 (round-robin dispatch), 80 slots each;
    // slots walk n fastest within 16 m-tiles per XCD.
    const int xcd = blockIdx.x & 7;
    const int idx = blockIdx.x >> 3;          // 0..79
    const int m0 = (xcd * 16 + idx / 5) * GBM;
    const int n0 = (idx % 5) * GBN;

    const int rm = lane & 15;
    const int kc = lane >> 4;

    floatx4 acc[4][4];
#pragma unroll
    for (int i = 0; i < 4; ++i)
#pragma unroll
        for (int j = 0; j < 4; ++j) acc[i][j] = (floatx4){0.f, 0.f, 0.f, 0.f};

    // staging: 512 16B-chunks per operand; thread does chunks tid, tid+256
    const int rowc0 = tid >> 2, sub0 = (tid & 3) * 8;
    const int rowc1 = (tid + 256) >> 2;

    for (int k0 = 0; k0 < HIDDEN; k0 += GBK) {
        async16(Xbf + (size_t)(m0 + rowc0) * HIDDEN + k0 + sub0, As + tid * 8);
        async16(Xbf + (size_t)(m0 + rowc1) * HIDDEN + k0 + sub0, As + (tid + 256) * 8);
        async16(Wbf + (size_t)(n0 + rowc0) * HIDDEN + k0 + sub0, Bs + tid * 8);
        async16(Wbf + (size_t)(n0 + rowc1) * HIDDEN + k0 + sub0, Bs + (tid + 256) * 8);
        __syncthreads();

        const short8* Asv = reinterpret_cast<const short8*>(As);
        const short8* Bsv = reinterpret_cast<const short8*>(Bs);
        short8 af[4], bfr[4];
#pragma unroll
        for (int f = 0; f < 4; ++f) {
            af[f]  = Asv[(wm * 64 + f * 16 + rm) * 4 + kc];
            bfr[f] = Bsv[(wn * 64 + f * 16 + rm) * 4 + kc];
        }
#pragma unroll
        for (int i = 0; i < 4; ++i)
#pragma unroll
            for (int j = 0; j < 4; ++j)
                acc[i][j] = __builtin_amdgcn_mfma_f32_16x16x32_bf16(
                    af[i], bfr[j], acc[i][j], 0, 0, 0);
        __syncthreads();
    }

    // epilogue: bias, cvt bf16, pair-pack via shfl, uint stores (even lanes)
    const int cl = lane & 15;
    const int r4 = (lane >> 4) * 4;
    float bj[4];
#pragma unroll
    for (int j = 0; j < 4; ++j) bj[j] = bias[n0 + wn * 64 + j * 16 + cl];

#pragma unroll
    for (int i = 0; i < 4; ++i)
#pragma unroll
        for (int j = 0; j < 4; ++j) {
            const int col = n0 + wn * 64 + j * 16 + cl;
#pragma unroll
            for (int q = 0; q < 4; ++q) {
                const int row = m0 + wm * 64 + i * 16 + r4 + q;
                unsigned v = f32_to_bf16(acc[i][j][q] + bj[j]);
                unsigned o = (unsigned)__shfl_xor((int)v, 1);
                if ((cl & 1) == 0)
                    *reinterpret_cast<uint*>(Lg + (size_t)row * NCOLS + col) =
                        v | (o << 16);
            }
        }
}

// ---------------- Quantize: gumbel-argmax / gather / softmax-marginal ----------------
// 32768 logit-rows; block = 32 rows (4 waves x 8 tasks). All gu/Lg loads
// batch-prefetched into registers before the compute chains.
__global__ __launch_bounds__(256) void quantize_kernel(
    const ushort* __restrict__ Lg,      // [16384,640] bf16
    const float* __restrict__ gu,       // [32768,320]
    const float* __restrict__ cv,       // [640,128]
    float* __restrict__ out,            // [16384,256]
    float* __restrict__ marginal)       // [640]
{
    __shared__ float smr[4][NVARS];
    const int tid = threadIdx.x;
    const int w = tid >> 6;
    const int lane = tid & 63;
    const int g = w & 1;               // each wave's rows share one group

    // batch prefetch: 8 tasks x (5 gu + 5 logits) per lane
    float ug[8][5], lg[8][5];
#pragma unroll
    for (int t = 0; t < 8; ++t) {
        const int r = blockIdx.x * 32 + t * 4 + w;
        const int n = r >> 1;
        const float* gp = gu + (size_t)r * NVARS + lane;
        const ushort* lp = Lg + (size_t)n * NCOLS + g * NVARS + lane;
#pragma unroll
        for (int j = 0; j < 5; ++j) {
            ug[t][j] = gp[j * 64];
            lg[t][j] = bf16_to_f32(lp[j * 64]);
        }
    }

    float macc[5];
#pragma unroll
    for (int j = 0; j < 5; ++j) macc[j] = 0.f;

#pragma unroll
    for (int t = 0; t < 8; ++t) {
        const int r = blockIdx.x * 32 + t * 4 + w;
        const int n = r >> 1;

        // argmax over key = lg - log(-log(u)), first-index tie-break
        float bk = lg[t][0] - __logf(-__logf(ug[t][0]));
        int bi = lane;
#pragma unroll
        for (int j = 1; j < 5; ++j) {
            const float kj = lg[t][j] - __logf(-__logf(ug[t][j]));
            const int v = lane + j * 64;
            if (kj > bk) { bk = kj; bi = v; }
        }
#pragma unroll
        for (int sh = 32; sh > 0; sh >>= 1) {
            const float ok = __shfl_xor(bk, sh);
            const int oi = __shfl_xor(bi, sh);
            if (ok > bk || (ok == bk && oi < bi)) { bk = ok; bi = oi; }
        }

        // softmax without max-subtraction (logits bounded ~|3.5|)
        float p[5], sume = 0.f;
#pragma unroll
        for (int j = 0; j < 5; ++j) { p[j] = __expf(lg[t][j]); sume += p[j]; }
#pragma unroll
        for (int sh = 32; sh > 0; sh >>= 1) sume += __shfl_xor(sume, sh);
        const float inv = 1.f / sume;
#pragma unroll
        for (int j = 0; j < 5; ++j) macc[j] += p[j] * inv;

        // gather selected codevector (128 f32 -> float2/lane)
        const float2* cvrow =
            reinterpret_cast<const float2*>(cv + (size_t)(g * NVARS + bi) * 128);
        reinterpret_cast<float2*>(out + (size_t)n * CVDIM + g * 128)[lane] = cvrow[lane];
    }

    // block-level marginal reduce: waves 0,2 -> group0; 1,3 -> group1
#pragma unroll
    for (int j = 0; j < 5; ++j) smr[w][lane + j * 64] = macc[j];
    __syncthreads();
    for (int i = tid; i < NVARS; i += 256) {
        atomicAdd(&marginal[i], smr[0][i] + smr[2][i]);
        atomicAdd(&marginal[NVARS + i], smr[1][i] + smr[3][i]);
    }
}

// ---------------- Perplexity finalize ----------------
__global__ void perplexity_kernel(const float* __restrict__ marginal,
                                  float* __restrict__ out)
{
    const int lane = threadIdx.x;
    float h0 = 0.0f, h1 = 0.0f;
    for (int v = lane; v < NVARS; v += 64) {
        const float m0 = marginal[v] * (1.0f / (float)NROWS);
        h0 += m0 * logf(m0 + 1e-7f);
        const float m1 = marginal[NVARS + v] * (1.0f / (float)NROWS);
        h1 += m1 * logf(m1 + 1e-7f);
    }
#pragma unroll
    for (int s = 32; s > 0; s >>= 1) {
        h0 += __shfl_xor(h0, s);
        h1 += __shfl_xor(h1, s);
    }
    if (lane == 0) out[OUT_ELEMS] = expf(-h0) + expf(-h1);
}

extern "C" void kernel_launch(void* const* d_in, const int* in_sizes, int n_in,
                              void* d_out, int out_size, void* d_ws, size_t ws_size,
                              hipStream_t stream) {
    const float* X    = (const float*)d_in[0];   // [8,2048,1024]
    const float* W    = (const float*)d_in[1];   // [640,1024]
    const float* bias = (const float*)d_in[2];   // [640]
    const float* cv   = (const float*)d_in[3];   // [1,640,128]
    const float* gu   = (const float*)d_in[4];   // [32768,320]
    float* out = (float*)d_out;

    ushort* Xbf      = (ushort*)d_ws;                             // 33.55 MB
    ushort* Wbf      = Xbf + (size_t)NROWS * HIDDEN;              // 1.31 MB
    ushort* Lg       = Wbf + (size_t)NCOLS * HIDDEN;              // 20.97 MB
    float*  marginal = (float*)(Lg + (size_t)NROWS * NCOLS);      // 2.56 KB

    (void)hipMemsetAsync(marginal, 0, NCOLS * sizeof(float), stream);

    convert_bf16_kernel<<<NROWS * HIDDEN / 8 / 256, 256, 0, stream>>>(
        X, Xbf, NROWS * HIDDEN / 8);
    convert_bf16_kernel<<<(NCOLS * HIDDEN / 8 + 255) / 256, 256, 0, stream>>>(
        W, Wbf, NCOLS * HIDDEN / 8);

    gemm_logits_kernel<<<(NROWS / GBM) * (NCOLS / GBN), 256, 0, stream>>>(
        Xbf, Wbf, bias, Lg);

    quantize_kernel<<<(NROWS * 2) / 32, 256, 0, stream>>>(
        Lg, gu, cv, out, marginal);

    perplexity_kernel<<<1, 64, 0, stream>>>(marginal, out);
}

// Round 13
// 82.248 us; speedup vs baseline: 1.9079x; 1.2328x over previous
//
#include <hip/hip_runtime.h>
#include <math.h>

// Problem constants
#define NROWS 16384                     // B*S
#define HIDDEN 1024
#define NVARS 320
#define NCOLS 640
#define CVDIM 256
#define OUT_ELEMS (NROWS * CVDIM)
#define NSHADOW 32

typedef __attribute__((ext_vector_type(8))) short short8;
typedef __attribute__((ext_vector_type(4))) float floatx4;

__device__ __forceinline__ unsigned f32_to_bf16(float f) {
    unsigned u = __builtin_bit_cast(unsigned, f);
    return (u + 0x7FFFu + ((u >> 16) & 1u)) >> 16;
}
__device__ __forceinline__ float bf16_to_f32(ushort u) {
    return __builtin_bit_cast(float, ((unsigned)u) << 16);
}

__global__ __launch_bounds__(256) void convert_bf16_kernel(
    const float* __restrict__ src, ushort* __restrict__ dst, int n8)
{
    const int i = blockIdx.x * 256 + threadIdx.x;
    if (i >= n8) return;
    const float4* s = reinterpret_cast<const float4*>(src) + (size_t)i * 2;
    const float4 v0 = s[0];
    const float4 v1 = s[1];
    uint4 p;
    p.x = f32_to_bf16(v0.x) | (f32_to_bf16(v0.y) << 16);
    p.y = f32_to_bf16(v0.z) | (f32_to_bf16(v0.w) << 16);
    p.z = f32_to_bf16(v1.x) | (f32_to_bf16(v1.y) << 16);
    p.w = f32_to_bf16(v1.z) | (f32_to_bf16(v1.w) << 16);
    reinterpret_cast<uint4*>(dst)[i] = p;
}

__device__ __forceinline__ void async16(const void* g, void* l) {
    __builtin_amdgcn_global_load_lds(
        (const __attribute__((address_space(1))) void*)g,
        (__attribute__((address_space(3))) void*)l,
        16, 0, 0);
}

// ---------------- GEMM (R2 structure, measured 27us): Lg = Xbf @ Wbf^T + b ----
// 128x128x32 tile, 256 threads = 4 waves (2x2), wave tile 64x64.
// BOTH operands bf16 via global_load_lds, single-buffered, 2 barriers/step.
#define GBM 128
#define GBN 128
#define GBK 32

__global__ __launch_bounds__(256) void gemm_logits_kernel(
    const ushort* __restrict__ Xbf,     // [16384,1024] bf16
    const ushort* __restrict__ Wbf,     // [640,1024] bf16
    const float* __restrict__ bias,     // [640]
    ushort* __restrict__ Lg)            // [16384,640] bf16
{
    __shared__ __align__(16) ushort As[4096];   // [128][32] bf16
    __shared__ __align__(16) ushort Bs[4096];

    const int tid = threadIdx.x;
    const int lane = tid & 63;
    const int w = tid >> 6;
    const int wm = w >> 1, wn = w & 1;

    const int m0 = blockIdx.x * GBM;
    const int n0 = blockIdx.y * GBN;

    const int rm = lane & 15;
    const int kc = lane >> 4;

    floatx4 acc[4][4];
#pragma unroll
    for (int i = 0; i < 4; ++i)
#pragma unroll
        for (int j = 0; j < 4; ++j) acc[i][j] = (floatx4){0.f, 0.f, 0.f, 0.f};

    // staging: 512 16B-chunks per operand; thread does chunks tid, tid+256
    const int rowc0 = tid >> 2, sub0 = (tid & 3) * 8;
    const int rowc1 = (tid + 256) >> 2;

    for (int k0 = 0; k0 < HIDDEN; k0 += GBK) {
        async16(Xbf + (size_t)(m0 + rowc0) * HIDDEN + k0 + sub0, As + tid * 8);
        async16(Xbf + (size_t)(m0 + rowc1) * HIDDEN + k0 + sub0, As + (tid + 256) * 8);
        async16(Wbf + (size_t)(n0 + rowc0) * HIDDEN + k0 + sub0, Bs + tid * 8);
        async16(Wbf + (size_t)(n0 + rowc1) * HIDDEN + k0 + sub0, Bs + (tid + 256) * 8);
        __syncthreads();

        const short8* Asv = reinterpret_cast<const short8*>(As);
        const short8* Bsv = reinterpret_cast<const short8*>(Bs);
        short8 af[4], bfr[4];
#pragma unroll
        for (int f = 0; f < 4; ++f) {
            af[f]  = Asv[(wm * 64 + f * 16 + rm) * 4 + kc];
            bfr[f] = Bsv[(wn * 64 + f * 16 + rm) * 4 + kc];
        }
#pragma unroll
        for (int i = 0; i < 4; ++i)
#pragma unroll
            for (int j = 0; j < 4; ++j)
                acc[i][j] = __builtin_amdgcn_mfma_f32_16x16x32_bf16(
                    af[i], bfr[j], acc[i][j], 0, 0, 0);
        __syncthreads();
    }

    // epilogue: bias, cvt bf16, pair-pack via shfl, uint stores (even lanes)
    const int cl = lane & 15;
    const int r4 = (lane >> 4) * 4;
    float bj[4];
#pragma unroll
    for (int j = 0; j < 4; ++j) bj[j] = bias[n0 + wn * 64 + j * 16 + cl];

#pragma unroll
    for (int i = 0; i < 4; ++i)
#pragma unroll
        for (int j = 0; j < 4; ++j) {
            const int col = n0 + wn * 64 + j * 16 + cl;
#pragma unroll
            for (int q = 0; q < 4; ++q) {
                const int row = m0 + wm * 64 + i * 16 + r4 + q;
                unsigned v = f32_to_bf16(acc[i][j][q] + bj[j]);
                unsigned o = (unsigned)__shfl_xor((int)v, 1);
                if ((cl & 1) == 0)
                    *reinterpret_cast<uint*>(Lg + (size_t)row * NCOLS + col) =
                        v | (o << 16);
            }
        }
}

// ---------------- Quantize: one output-row n per wave ----------------
// 4096 blocks x 4 waves; wave handles logit rows 2n (group0) and 2n+1 (group1).
// Both tasks' loads up front; both cv gathers issued together; marginal via
// block LDS reduce -> 32-shadow atomics (contention 128/address).
__global__ __launch_bounds__(256) void quantize_kernel(
    const ushort* __restrict__ Lg,      // [16384,640] bf16
    const float* __restrict__ gu,       // [32768,320]
    const float* __restrict__ cv,       // [640,128]
    float* __restrict__ out,            // [16384,256] (+1 ppl)
    float* __restrict__ shadow)         // [32][640]
{
    __shared__ float smr[4][NCOLS];
    const int tid = threadIdx.x;
    const int w = tid >> 6;
    const int lane = tid & 63;

    const int n = blockIdx.x * 4 + w;   // output row

    // load both groups' logits and gumbel noise (20 values, all independent)
    float lg[2][5], ug[2][5];
    const ushort* lp = Lg + (size_t)n * NCOLS + lane;
    const float* gp = gu + (size_t)(2 * n) * NVARS + lane;
#pragma unroll
    for (int g = 0; g < 2; ++g)
#pragma unroll
        for (int j = 0; j < 5; ++j) {
            lg[g][j] = bf16_to_f32(lp[g * NVARS + j * 64]);
            ug[g][j] = gp[g * NVARS + j * 64];
        }

    // argmax for both groups (first-index tie-break)
    int bi[2];
#pragma unroll
    for (int g = 0; g < 2; ++g) {
        float bk = lg[g][0] - __logf(-__logf(ug[g][0]));
        int b = lane;
#pragma unroll
        for (int j = 1; j < 5; ++j) {
            const float kj = lg[g][j] - __logf(-__logf(ug[g][j]));
            const int v = lane + j * 64;
            if (kj > bk) { bk = kj; b = v; }
        }
#pragma unroll
        for (int sh = 32; sh > 0; sh >>= 1) {
            const float ok = __shfl_xor(bk, sh);
            const int oi = __shfl_xor(b, sh);
            if (ok > bk || (ok == bk && oi < b)) { bk = ok; b = oi; }
        }
        bi[g] = b;
    }

    // both codevector gathers in flight together
    const float2 c0 = reinterpret_cast<const float2*>(cv + (size_t)bi[0] * 128)[lane];
    const float2 c1 = reinterpret_cast<const float2*>(cv + (size_t)(NVARS + bi[1]) * 128)[lane];

    // softmax (no max-subtraction; logits bounded ~|3.5|) -> smr
#pragma unroll
    for (int g = 0; g < 2; ++g) {
        float p[5], sume = 0.f;
#pragma unroll
        for (int j = 0; j < 5; ++j) { p[j] = __expf(lg[g][j]); sume += p[j]; }
#pragma unroll
        for (int sh = 32; sh > 0; sh >>= 1) sume += __shfl_xor(sume, sh);
        const float inv = 1.f / sume;
#pragma unroll
        for (int j = 0; j < 5; ++j)
            smr[w][g * NVARS + lane + j * 64] = p[j] * inv;
    }

    // output stores (row n: group0 -> [0,128), group1 -> [128,256))
    float2* orow = reinterpret_cast<float2*>(out + (size_t)n * CVDIM);
    orow[lane] = c0;
    orow[64 + lane] = c1;

    // block reduce -> one shadow atomic per column
    __syncthreads();
    float* sh0 = shadow + (blockIdx.x & (NSHADOW - 1)) * NCOLS;
    for (int i = tid; i < NCOLS; i += 256)
        atomicAdd(&sh0[i], smr[0][i] + smr[1][i] + smr[2][i] + smr[3][i]);
}

// ---------------- Perplexity finalize (sums 32 shadows) ----------------
__global__ void perplexity_kernel(const float* __restrict__ shadow,
                                  float* __restrict__ out)
{
    const int lane = threadIdx.x;   // 64 threads
    float h0 = 0.0f, h1 = 0.0f;
    for (int v = lane; v < NVARS; v += 64) {
        float s0 = 0.f, s1 = 0.f;
#pragma unroll
        for (int sh = 0; sh < NSHADOW; ++sh) {
            s0 += shadow[sh * NCOLS + v];
            s1 += shadow[sh * NCOLS + NVARS + v];
        }
        const float m0 = s0 * (1.0f / (float)NROWS);
        h0 += m0 * logf(m0 + 1e-7f);
        const float m1 = s1 * (1.0f / (float)NROWS);
        h1 += m1 * logf(m1 + 1e-7f);
    }
#pragma unroll
    for (int s = 32; s > 0; s >>= 1) {
        h0 += __shfl_xor(h0, s);
        h1 += __shfl_xor(h1, s);
    }
    if (lane == 0) out[OUT_ELEMS] = expf(-h0) + expf(-h1);
}

extern "C" void kernel_launch(void* const* d_in, const int* in_sizes, int n_in,
                              void* d_out, int out_size, void* d_ws, size_t ws_size,
                              hipStream_t stream) {
    const float* X    = (const float*)d_in[0];   // [8,2048,1024]
    const float* W    = (const float*)d_in[1];   // [640,1024]
    const float* bias = (const float*)d_in[2];   // [640]
    const float* cv   = (const float*)d_in[3];   // [1,640,128]
    const float* gu   = (const float*)d_in[4];   // [32768,320]
    float* out = (float*)d_out;

    ushort* Xbf    = (ushort*)d_ws;                             // 33.55 MB
    ushort* Wbf    = Xbf + (size_t)NROWS * HIDDEN;              // 1.31 MB
    ushort* Lg     = Wbf + (size_t)NCOLS * HIDDEN;              // 20.97 MB
    float*  shadow = (float*)(Lg + (size_t)NROWS * NCOLS);      // 80 KB

    (void)hipMemsetAsync(shadow, 0, NSHADOW * NCOLS * sizeof(float), stream);

    convert_bf16_kernel<<<NROWS * HIDDEN / 8 / 256, 256, 0, stream>>>(
        X, Xbf, NROWS * HIDDEN / 8);
    convert_bf16_kernel<<<(NCOLS * HIDDEN / 8 + 255) / 256, 256, 0, stream>>>(
        W, Wbf, NCOLS * HIDDEN / 8);

    dim3 ggrid(NROWS / GBM, NCOLS / GBN);   // (128, 5)
    gemm_logits_kernel<<<ggrid, 256, 0, stream>>>(Xbf, Wbf, bias, Lg);

    quantize_kernel<<<NROWS / 4, 256, 0, stream>>>(Lg, gu, cv, out, shadow);

    perplexity_kernel<<<1, 64, 0, stream>>>(shadow, out);
}

// Round 14
// 75.081 us; speedup vs baseline: 2.0901x; 1.0955x over previous
//
#include <hip/hip_runtime.h>
#include <math.h>

// Problem constants
#define NROWS 16384                     // B*S
#define HIDDEN 1024
#define NVARS 320
#define NCOLS 640
#define CVDIM 256
#define OUT_ELEMS (NROWS * CVDIM)
#define NSHADOW 32

typedef __attribute__((ext_vector_type(8))) short short8;
typedef __attribute__((ext_vector_type(4))) float floatx4;

__device__ __forceinline__ unsigned f32_to_bf16(float f) {
    unsigned u = __builtin_bit_cast(unsigned, f);
    return (u + 0x7FFFu + ((u >> 16) & 1u)) >> 16;
}
__device__ __forceinline__ float bf16_to_f32(ushort u) {
    return __builtin_bit_cast(float, ((unsigned)u) << 16);
}

// convert + (optionally) zero a small buffer (removes a memset node from the graph)
__global__ __launch_bounds__(256) void convert_bf16_kernel(
    const float* __restrict__ src, ushort* __restrict__ dst, int n8,
    float* __restrict__ zbuf, int zn)
{
    const int i = blockIdx.x * 256 + threadIdx.x;
    if (i < zn) zbuf[i] = 0.0f;
    if (i >= n8) return;
    const float4* s = reinterpret_cast<const float4*>(src) + (size_t)i * 2;
    const float4 v0 = s[0];
    const float4 v1 = s[1];
    uint4 p;
    p.x = f32_to_bf16(v0.x) | (f32_to_bf16(v0.y) << 16);
    p.y = f32_to_bf16(v0.z) | (f32_to_bf16(v0.w) << 16);
    p.z = f32_to_bf16(v1.x) | (f32_to_bf16(v1.y) << 16);
    p.w = f32_to_bf16(v1.z) | (f32_to_bf16(v1.w) << 16);
    reinterpret_cast<uint4*>(dst)[i] = p;
}

__device__ __forceinline__ void async16(const void* g, void* l) {
    __builtin_amdgcn_global_load_lds(
        (const __attribute__((address_space(1))) void*)g,
        (__attribute__((address_space(3))) void*)l,
        16, 0, 0);
}

// ---------------- GEMM (R2 structure, measured ~27us): Lg = Xbf @ Wbf^T + b ----
#define GBM 128
#define GBN 128
#define GBK 32

__global__ __launch_bounds__(256) void gemm_logits_kernel(
    const ushort* __restrict__ Xbf,     // [16384,1024] bf16
    const ushort* __restrict__ Wbf,     // [640,1024] bf16
    const float* __restrict__ bias,     // [640]
    ushort* __restrict__ Lg)            // [16384,640] bf16
{
    __shared__ __align__(16) ushort As[4096];   // [128][32] bf16
    __shared__ __align__(16) ushort Bs[4096];

    const int tid = threadIdx.x;
    const int lane = tid & 63;
    const int w = tid >> 6;
    const int wm = w >> 1, wn = w & 1;

    const int m0 = blockIdx.x * GBM;
    const int n0 = blockIdx.y * GBN;

    const int rm = lane & 15;
    const int kc = lane >> 4;

    floatx4 acc[4][4];
#pragma unroll
    for (int i = 0; i < 4; ++i)
#pragma unroll
        for (int j = 0; j < 4; ++j) acc[i][j] = (floatx4){0.f, 0.f, 0.f, 0.f};

    const int rowc0 = tid >> 2, sub0 = (tid & 3) * 8;
    const int rowc1 = (tid + 256) >> 2;

    for (int k0 = 0; k0 < HIDDEN; k0 += GBK) {
        async16(Xbf + (size_t)(m0 + rowc0) * HIDDEN + k0 + sub0, As + tid * 8);
        async16(Xbf + (size_t)(m0 + rowc1) * HIDDEN + k0 + sub0, As + (tid + 256) * 8);
        async16(Wbf + (size_t)(n0 + rowc0) * HIDDEN + k0 + sub0, Bs + tid * 8);
        async16(Wbf + (size_t)(n0 + rowc1) * HIDDEN + k0 + sub0, Bs + (tid + 256) * 8);
        __syncthreads();

        const short8* Asv = reinterpret_cast<const short8*>(As);
        const short8* Bsv = reinterpret_cast<const short8*>(Bs);
        short8 af[4], bfr[4];
#pragma unroll
        for (int f = 0; f < 4; ++f) {
            af[f]  = Asv[(wm * 64 + f * 16 + rm) * 4 + kc];
            bfr[f] = Bsv[(wn * 64 + f * 16 + rm) * 4 + kc];
        }
#pragma unroll
        for (int i = 0; i < 4; ++i)
#pragma unroll
            for (int j = 0; j < 4; ++j)
                acc[i][j] = __builtin_amdgcn_mfma_f32_16x16x32_bf16(
                    af[i], bfr[j], acc[i][j], 0, 0, 0);
        __syncthreads();
    }

    const int cl = lane & 15;
    const int r4 = (lane >> 4) * 4;
    float bj[4];
#pragma unroll
    for (int j = 0; j < 4; ++j) bj[j] = bias[n0 + wn * 64 + j * 16 + cl];

#pragma unroll
    for (int i = 0; i < 4; ++i)
#pragma unroll
        for (int j = 0; j < 4; ++j) {
            const int col = n0 + wn * 64 + j * 16 + cl;
#pragma unroll
            for (int q = 0; q < 4; ++q) {
                const int row = m0 + wm * 64 + i * 16 + r4 + q;
                unsigned v = f32_to_bf16(acc[i][j][q] + bj[j]);
                unsigned o = (unsigned)__shfl_xor((int)v, 1);
                if ((cl & 1) == 0)
                    *reinterpret_cast<uint*>(Lg + (size_t)row * NCOLS + col) =
                        v | (o << 16);
            }
        }
}

// ---------------- Quantize: TWO output rows per wave (ILP x2) ----------------
// 2048 blocks x 4 waves; wave w handles rows n0 = bid*4+w and n1 = n0+8192.
// All 40 loads issued up front; 4 independent argmax trees; 4 gathers in flight.
__global__ __launch_bounds__(256) void quantize_kernel(
    const ushort* __restrict__ Lg,      // [16384,640] bf16
    const float* __restrict__ gu,       // [32768,320]
    const float* __restrict__ cv,       // [640,128]
    float* __restrict__ out,            // [16384,256] (+1 ppl)
    float* __restrict__ shadow)         // [32][640]
{
    __shared__ float smr[4][NCOLS];
    const int tid = threadIdx.x;
    const int w = tid >> 6;
    const int lane = tid & 63;

    const int n0 = blockIdx.x * 4 + w;
    const int n1 = n0 + 8192;

    // loads: 2 rows x 2 groups x 5
    float lg[2][2][5], ug[2][2][5];
#pragma unroll
    for (int r = 0; r < 2; ++r) {
        const int n = r ? n1 : n0;
        const ushort* lp = Lg + (size_t)n * NCOLS + lane;
        const float* gp = gu + (size_t)(2 * n) * NVARS + lane;
#pragma unroll
        for (int g = 0; g < 2; ++g)
#pragma unroll
            for (int j = 0; j < 5; ++j) {
                lg[r][g][j] = bf16_to_f32(lp[g * NVARS + j * 64]);
                ug[r][g][j] = gp[g * NVARS + j * 64];
            }
    }

    // 4 independent argmaxes (first-index tie-break)
    int bi[2][2];
#pragma unroll
    for (int r = 0; r < 2; ++r)
#pragma unroll
        for (int g = 0; g < 2; ++g) {
            float bk = lg[r][g][0] - __logf(-__logf(ug[r][g][0]));
            int b = lane;
#pragma unroll
            for (int j = 1; j < 5; ++j) {
                const float kj = lg[r][g][j] - __logf(-__logf(ug[r][g][j]));
                const int v = lane + j * 64;
                if (kj > bk) { bk = kj; b = v; }
            }
#pragma unroll
            for (int sh = 32; sh > 0; sh >>= 1) {
                const float ok = __shfl_xor(bk, sh);
                const int oi = __shfl_xor(b, sh);
                if (ok > bk || (ok == bk && oi < b)) { bk = ok; b = oi; }
            }
            bi[r][g] = b;
        }

    // 4 codevector gathers in flight together
    float2 c[2][2];
#pragma unroll
    for (int r = 0; r < 2; ++r) {
        c[r][0] = reinterpret_cast<const float2*>(cv + (size_t)bi[r][0] * 128)[lane];
        c[r][1] = reinterpret_cast<const float2*>(cv + (size_t)(NVARS + bi[r][1]) * 128)[lane];
    }

    // softmax (no max-subtraction; logits bounded ~|3.5|); combine both rows
#pragma unroll
    for (int g = 0; g < 2; ++g) {
        float pr[2][5];
#pragma unroll
        for (int r = 0; r < 2; ++r) {
            float sume = 0.f;
#pragma unroll
            for (int j = 0; j < 5; ++j) { pr[r][j] = __expf(lg[r][g][j]); sume += pr[r][j]; }
#pragma unroll
            for (int sh = 32; sh > 0; sh >>= 1) sume += __shfl_xor(sume, sh);
            const float inv = 1.f / sume;
#pragma unroll
            for (int j = 0; j < 5; ++j) pr[r][j] *= inv;
        }
#pragma unroll
        for (int j = 0; j < 5; ++j)
            smr[w][g * NVARS + lane + j * 64] = pr[0][j] + pr[1][j];
    }

    // output stores
    float2* o0 = reinterpret_cast<float2*>(out + (size_t)n0 * CVDIM);
    o0[lane] = c[0][0];
    o0[64 + lane] = c[0][1];
    float2* o1 = reinterpret_cast<float2*>(out + (size_t)n1 * CVDIM);
    o1[lane] = c[1][0];
    o1[64 + lane] = c[1][1];

    // block reduce -> one shadow atomic per column
    __syncthreads();
    float* sh0 = shadow + (blockIdx.x & (NSHADOW - 1)) * NCOLS;
    for (int i = tid; i < NCOLS; i += 256)
        atomicAdd(&sh0[i], smr[0][i] + smr[1][i] + smr[2][i] + smr[3][i]);
}

// ---------------- Perplexity finalize (parallel, 256 threads) ----------------
__global__ __launch_bounds__(256) void perplexity_kernel(
    const float* __restrict__ shadow, float* __restrict__ out)
{
    __shared__ float r0[4], r1[4];
    const int tid = threadIdx.x;
    float h0 = 0.f, h1 = 0.f;
    for (int cidx = tid; cidx < NCOLS; cidx += 256) {
        float s = 0.f;
#pragma unroll
        for (int sh = 0; sh < NSHADOW; ++sh) s += shadow[sh * NCOLS + cidx];
        const float m = s * (1.0f / (float)NROWS);
        const float t = m * logf(m + 1e-7f);
        if (cidx < NVARS) h0 += t; else h1 += t;
    }
#pragma unroll
    for (int s = 32; s > 0; s >>= 1) {
        h0 += __shfl_xor(h0, s);
        h1 += __shfl_xor(h1, s);
    }
    if ((tid & 63) == 0) { r0[tid >> 6] = h0; r1[tid >> 6] = h1; }
    __syncthreads();
    if (tid == 0)
        out[OUT_ELEMS] = expf(-(r0[0] + r0[1] + r0[2] + r0[3])) +
                         expf(-(r1[0] + r1[1] + r1[2] + r1[3]));
}

extern "C" void kernel_launch(void* const* d_in, const int* in_sizes, int n_in,
                              void* d_out, int out_size, void* d_ws, size_t ws_size,
                              hipStream_t stream) {
    const float* X    = (const float*)d_in[0];   // [8,2048,1024]
    const float* W    = (const float*)d_in[1];   // [640,1024]
    const float* bias = (const float*)d_in[2];   // [640]
    const float* cv   = (const float*)d_in[3];   // [1,640,128]
    const float* gu   = (const float*)d_in[4];   // [32768,320]
    float* out = (float*)d_out;

    ushort* Xbf    = (ushort*)d_ws;                             // 33.55 MB
    ushort* Wbf    = Xbf + (size_t)NROWS * HIDDEN;              // 1.31 MB
    ushort* Lg     = Wbf + (size_t)NCOLS * HIDDEN;              // 20.97 MB
    float*  shadow = (float*)(Lg + (size_t)NROWS * NCOLS);      // 80 KB

    // X convert also zeroes the shadow accumulators (no memset node)
    convert_bf16_kernel<<<NROWS * HIDDEN / 8 / 256, 256, 0, stream>>>(
        X, Xbf, NROWS * HIDDEN / 8, shadow, NSHADOW * NCOLS);
    convert_bf16_kernel<<<(NCOLS * HIDDEN / 8 + 255) / 256, 256, 0, stream>>>(
        W, Wbf, NCOLS * HIDDEN / 8, (float*)nullptr, 0);

    dim3 ggrid(NROWS / GBM, NCOLS / GBN);   // (128, 5)
    gemm_logits_kernel<<<ggrid, 256, 0, stream>>>(Xbf, Wbf, bias, Lg);

    quantize_kernel<<<NROWS / 2 / 4, 256, 0, stream>>>(Lg, gu, cv, out, shadow);

    perplexity_kernel<<<1, 256, 0, stream>>>(shadow, out);
}